// Round 10
// baseline (651.984 us; speedup 1.0000x reference)
//
#include <hip/hip_runtime.h>
#include <math.h>

// ---------------------------------------------------------------------------
// GCN pipeline: conv1(relu) -> conv2(relu) -> quantize(+reg) -> add -> conv3
// GEMMs + quantize-prods: split-bf16 MFMA (Ootomo 3-term), pre-split tables.
// Norm folding: gemm epilogue scales row r by dinv[r]; aggregation is pure
// gather-sum * dinv[node] + bias (csr_norm eliminated).
// ---------------------------------------------------------------------------

typedef short bf16x8 __attribute__((ext_vector_type(8)));
typedef float f32x4 __attribute__((ext_vector_type(4)));

__device__ __forceinline__ unsigned short bf16_rne(float a) {
    unsigned u = __builtin_bit_cast(unsigned, a);
    return (unsigned short)((u + 0x7FFFu + ((u >> 16) & 1u)) >> 16);
}
__device__ __forceinline__ float bf16_to_f(unsigned short h) {
    return __builtin_bit_cast(float, (unsigned)h << 16);
}
__device__ __forceinline__ void split4(const float* e, unsigned short* h, unsigned short* l) {
#pragma unroll
    for (int t = 0; t < 4; ++t) {
        h[t] = bf16_rne(e[t]);
        l[t] = bf16_rne(e[t] - bf16_to_f(h[t]));
    }
}

// ---------------- CSR build ----------------

__global__ void k_init(int* cnt, int* cursor, int* counter, float* balance, int n) {
    int i = blockIdx.x * blockDim.x + threadIdx.x;
    if (i < n) { cnt[i] = 0; cursor[i] = 0; }
    if (i < 480) balance[i] = 0.f;
    if (i == 0) *counter = 0;
}

__global__ void k_count(const int* __restrict__ dst, int* __restrict__ cnt, int e) {
    int i = blockIdx.x * blockDim.x + threadIdx.x;
    if (i < e) atomicAdd(&cnt[dst[i]], 1);
}

__global__ void k_allocdinv(const int* __restrict__ cnt, int* __restrict__ row_start,
                            int* __restrict__ counter, float* __restrict__ dinv, int n) {
    int i = blockIdx.x * blockDim.x + threadIdx.x;
    if (i < n) {
        row_start[i] = atomicAdd(counter, cnt[i]);
        dinv[i] = rsqrtf((float)cnt[i] + 1.0f);   // +1 self loop
    }
}

__global__ void k_fill(const int* __restrict__ src, const int* __restrict__ dst,
                       const int* __restrict__ row_start, int* __restrict__ cursor,
                       int* __restrict__ csr_src, int e) {
    int i = blockIdx.x * blockDim.x + threadIdx.x;
    if (i >= e) return;
    int s = src[i], d = dst[i];
    int slot = atomicAdd(&cursor[d], 1);
    csr_src[row_start[d] + slot] = s;
}

// ---------------- split kernels ----------------
// W0[256x256],W1[256x256],W2[256x128] -> transposed hi/lo [N][256];
// cent[120x256] -> hi/lo [128][256] (rows 120..127 zeroed).

__global__ void k_splitWC(const float* __restrict__ W0, const float* __restrict__ W1,
                          const float* __restrict__ W2, const float* __restrict__ cent,
                          short* __restrict__ w0h, short* __restrict__ w0l,
                          short* __restrict__ w1h, short* __restrict__ w1l,
                          short* __restrict__ w2h, short* __restrict__ w2l,
                          short* __restrict__ ch, short* __restrict__ cl) {
    int i = blockIdx.x * blockDim.x + threadIdx.x;
    float v;
    short *ph, *pl;
    int j;
    if (i < 65536) {
        j = i; v = W0[(j & 255) * 256 + (j >> 8)]; ph = w0h; pl = w0l;
    } else if (i < 131072) {
        j = i - 65536; v = W1[(j & 255) * 256 + (j >> 8)]; ph = w1h; pl = w1l;
    } else if (i < 163840) {
        j = i - 131072; v = W2[(j & 255) * 128 + (j >> 8)]; ph = w2h; pl = w2l;
    } else {
        j = i - 163840; int c = j >> 8;
        v = (c < 120) ? cent[j] : 0.f; ph = ch; pl = cl;
    }
    unsigned short h = bf16_rne(v);
    ph[j] = (short)h;
    pl[j] = (short)bf16_rne(v - bf16_to_f(h));
}

__global__ void k_splitA(const float* __restrict__ X, short* __restrict__ Hi,
                         short* __restrict__ Lo, int total8) {
    int i = blockIdx.x * blockDim.x + threadIdx.x;
    if (i >= total8) return;
    float4 a = *(const float4*)(X + (size_t)i * 8);
    float4 b = *(const float4*)(X + (size_t)i * 8 + 4);
    float e0[4] = {a.x, a.y, a.z, a.w}, e1[4] = {b.x, b.y, b.z, b.w};
    unsigned short h0[4], l0[4], h1[4], l1[4];
    split4(e0, h0, l0);
    split4(e1, h1, l1);
    *(uint4*)(Hi + (size_t)i * 8) = make_uint4(h0[0] | (h0[1] << 16), h0[2] | (h0[3] << 16),
                                              h1[0] | (h1[1] << 16), h1[2] | (h1[3] << 16));
    *(uint4*)(Lo + (size_t)i * 8) = make_uint4(l0[0] | (l0[1] << 16), l0[2] | (l0[3] << 16),
                                              l1[0] | (l1[1] << 16), l1[2] | (l1[3] << 16));
}

// ---------------- bf16-split MFMA GEMM (dinv-scaled epilogue) ----------------

__global__ __launch_bounds__(256, 2) void k_gemm_bf16s(const short* __restrict__ Ah,
                                                       const short* __restrict__ Al,
                                                       const short* __restrict__ Bh,
                                                       const short* __restrict__ Bl,
                                                       const float* __restrict__ dinv,
                                                       float* __restrict__ C,
                                                       int M, int N) {
    __shared__ short smem[4 * 128 * 56];   // Ash|Asl|Bsh|Bsl; epilogue f32[128][68]
    short* Ash = smem;
    short* Asl = smem + 7168;
    short* Bsh = smem + 14336;
    short* Bsl = smem + 21504;
    const int tid = threadIdx.x;
    const int bm = blockIdx.x * 128;
    const int bn = blockIdx.y * 128;
    const int wave = tid >> 6, lane = tid & 63;
    const int wr = wave >> 1, wc = wave & 1;
    const int lr = lane & 15, lk = lane >> 4;

    int srow[2], ssg[2];
    bool aval[2];
#pragma unroll
    for (int it = 0; it < 2; ++it) {
        int u = it * 256 + tid;
        srow[it] = u >> 2;
        ssg[it] = (u & 3) << 3;
        aval[it] = (bm + srow[it]) < M;
    }

    const bf16x8 z8 = {0, 0, 0, 0, 0, 0, 0, 0};
    bf16x8 pah[2], pal[2], pbh[2], pbl[2];

    auto prefetch = [&](int k0) {
#pragma unroll
        for (int it = 0; it < 2; ++it) {
            size_t arow = (size_t)(bm + srow[it]) * 256 + k0 + ssg[it];
            size_t brow = (size_t)(bn + srow[it]) * 256 + k0 + ssg[it];
            pah[it] = aval[it] ? *(const bf16x8*)(Ah + arow) : z8;
            pal[it] = aval[it] ? *(const bf16x8*)(Al + arow) : z8;
            pbh[it] = *(const bf16x8*)(Bh + brow);
            pbl[it] = *(const bf16x8*)(Bl + brow);
        }
    };

    f32x4 acc[4][4] = {};
    prefetch(0);

    for (int k0 = 0; k0 < 256; k0 += 32) {
#pragma unroll
        for (int it = 0; it < 2; ++it) {
            int off = srow[it] * 56 + ssg[it];
            *(bf16x8*)&Ash[off] = pah[it];
            *(bf16x8*)&Asl[off] = pal[it];
            *(bf16x8*)&Bsh[off] = pbh[it];
            *(bf16x8*)&Bsl[off] = pbl[it];
        }
        __syncthreads();

        bf16x8 ah[4], al[4], bh[4], bl[4];
#pragma unroll
        for (int i = 0; i < 4; ++i) {
            int off = (wr * 64 + i * 16 + lr) * 56 + lk * 8;
            ah[i] = *(bf16x8*)&Ash[off];
            al[i] = *(bf16x8*)&Asl[off];
        }
#pragma unroll
        for (int j = 0; j < 4; ++j) {
            int off = (wc * 64 + j * 16 + lr) * 56 + lk * 8;
            bh[j] = *(bf16x8*)&Bsh[off];
            bl[j] = *(bf16x8*)&Bsl[off];
        }

        if (k0 < 224) prefetch(k0 + 32);

#pragma unroll
        for (int i = 0; i < 4; ++i)
#pragma unroll
            for (int j = 0; j < 4; ++j) {
                acc[i][j] = __builtin_amdgcn_mfma_f32_16x16x32_bf16(al[i], bh[j], acc[i][j], 0, 0, 0);
                acc[i][j] = __builtin_amdgcn_mfma_f32_16x16x32_bf16(ah[i], bl[j], acc[i][j], 0, 0, 0);
                acc[i][j] = __builtin_amdgcn_mfma_f32_16x16x32_bf16(ah[i], bh[j], acc[i][j], 0, 0, 0);
            }
        __syncthreads();
    }

    // coalesced epilogue, row-scaled by dinv (C/D: col=lane&15, row=(lane>>4)*4+reg)
    float* Cs = (float*)smem;
#pragma unroll
    for (int p = 0; p < 2; ++p) {
        if (wc == p) {
#pragma unroll
            for (int i = 0; i < 4; ++i)
#pragma unroll
                for (int r = 0; r < 4; ++r) {
                    int row = wr * 64 + i * 16 + lk * 4 + r;
#pragma unroll
                    for (int j = 0; j < 4; ++j)
                        Cs[row * 68 + j * 16 + lr] = acc[i][j][r];
                }
        }
        __syncthreads();
#pragma unroll
        for (int t = 0; t < 8; ++t) {
            int idx = t * 256 + tid;
            int row = idx >> 4, c4 = idx & 15;
            if (bm + row < M) {
                float s = dinv[bm + row];
                float4 v = *(const float4*)&Cs[row * 68 + c4 * 4];
                v.x *= s; v.y *= s; v.z *= s; v.w *= s;
                *(float4*)(C + (size_t)(bm + row) * N + bn + p * 64 + c4 * 4) = v;
            }
        }
        __syncthreads();
    }
}

// ---------------- Aggregation (pure gather-sum over CSR) ----------------
// L3-BW-bound floor ~125us (rounds 4-6 invariant). xws rows are pre-scaled by
// dinv[src]; out = dinv[node]*(self + sum) + bias. SPLIT: emit bf16 hi/lo.

template <bool RELU, int MODE>
__global__ __launch_bounds__(256, 4) void k_agg4(const float* __restrict__ xw,
                                                 const float* __restrict__ dinv,
                                                 const int* __restrict__ csr_src,
                                                 const int* __restrict__ row_start,
                                                 const int* __restrict__ cnt,
                                                 const float* __restrict__ bias,
                                                 float* __restrict__ out,
                                                 short* __restrict__ outH,
                                                 short* __restrict__ outL, int n) {
    int node = blockIdx.x * 4 + (threadIdx.x >> 6);
    if (node >= n) return;
    int lane = threadIdx.x & 63;
    int c = lane * 4;
    float4 self = *(const float4*)(xw + (size_t)node * 256 + c);
    float ax = self.x, ay = self.y, az = self.z, aw = self.w;
    int st = row_start[node];
    int m = cnt[node];
    for (int t0 = 0; t0 < m; t0 += 64) {
        int rem = m - t0;
        int cnt_i = rem < 64 ? rem : 64;
        int idx_l = 0;
        if (lane < cnt_i) idx_l = csr_src[st + t0 + lane];
        int t = 0;
        for (; t + 8 <= cnt_i; t += 8) {
            const float* p0 = xw + (size_t)__shfl(idx_l, t + 0, 64) * 256 + c;
            const float* p1 = xw + (size_t)__shfl(idx_l, t + 1, 64) * 256 + c;
            const float* p2 = xw + (size_t)__shfl(idx_l, t + 2, 64) * 256 + c;
            const float* p3 = xw + (size_t)__shfl(idx_l, t + 3, 64) * 256 + c;
            const float* p4 = xw + (size_t)__shfl(idx_l, t + 4, 64) * 256 + c;
            const float* p5 = xw + (size_t)__shfl(idx_l, t + 5, 64) * 256 + c;
            const float* p6 = xw + (size_t)__shfl(idx_l, t + 6, 64) * 256 + c;
            const float* p7 = xw + (size_t)__shfl(idx_l, t + 7, 64) * 256 + c;
            float4 v0 = *(const float4*)p0;
            float4 v1 = *(const float4*)p1;
            float4 v2 = *(const float4*)p2;
            float4 v3 = *(const float4*)p3;
            float4 v4 = *(const float4*)p4;
            float4 v5 = *(const float4*)p5;
            float4 v6 = *(const float4*)p6;
            float4 v7 = *(const float4*)p7;
            ax += v0.x; ay += v0.y; az += v0.z; aw += v0.w;
            ax += v1.x; ay += v1.y; az += v1.z; aw += v1.w;
            ax += v2.x; ay += v2.y; az += v2.z; aw += v2.w;
            ax += v3.x; ay += v3.y; az += v3.z; aw += v3.w;
            ax += v4.x; ay += v4.y; az += v4.z; aw += v4.w;
            ax += v5.x; ay += v5.y; az += v5.z; aw += v5.w;
            ax += v6.x; ay += v6.y; az += v6.z; aw += v6.w;
            ax += v7.x; ay += v7.y; az += v7.z; aw += v7.w;
        }
        for (; t < cnt_i; ++t) {
            int s = __shfl(idx_l, t, 64);
            float4 v = *(const float4*)(xw + (size_t)s * 256 + c);
            ax += v.x; ay += v.y; az += v.z; aw += v.w;
        }
    }
    float di = dinv[node];
    float4 bv = *(const float4*)(bias + c);
    ax = ax * di + bv.x;
    ay = ay * di + bv.y;
    az = az * di + bv.z;
    aw = aw * di + bv.w;
    if (RELU) {
        ax = ax > 0.f ? ax : 0.5f * ax;
        ay = ay > 0.f ? ay : 0.5f * ay;
        az = az > 0.f ? az : 0.5f * az;
        aw = aw > 0.f ? aw : 0.5f * aw;
    }
    if (MODE == 0) {
        *(float4*)(out + (size_t)node * 256 + c) = make_float4(ax, ay, az, aw);
    } else {
        float e[4] = {ax, ay, az, aw};
        unsigned short h[4], l[4];
        split4(e, h, l);
        size_t o = (size_t)node * 256 + c;
        *(uint2*)(outH + o) = make_uint2(h[0] | (h[1] << 16), h[2] | (h[3] << 16));
        *(uint2*)(outL + o) = make_uint2(l[0] | (l[1] << 16), l[2] | (l[3] << 16));
    }
}

__global__ __launch_bounds__(256, 4) void k_agg2(const float* __restrict__ xw,
                                                 const float* __restrict__ dinv,
                                                 const int* __restrict__ csr_src,
                                                 const int* __restrict__ row_start,
                                                 const int* __restrict__ cnt,
                                                 const float* __restrict__ bias,
                                                 float* __restrict__ out, int n) {
    int node = blockIdx.x * 4 + (threadIdx.x >> 6);
    if (node >= n) return;
    int lane = threadIdx.x & 63;
    int c = lane * 2;
    float2 self = *(const float2*)(xw + (size_t)node * 128 + c);
    float ax = self.x, ay = self.y;
    int st = row_start[node];
    int m = cnt[node];
    for (int t0 = 0; t0 < m; t0 += 64) {
        int rem = m - t0;
        int cnt_i = rem < 64 ? rem : 64;
        int idx_l = 0;
        if (lane < cnt_i) idx_l = csr_src[st + t0 + lane];
        int t = 0;
        for (; t + 8 <= cnt_i; t += 8) {
            const float* p0 = xw + (size_t)__shfl(idx_l, t + 0, 64) * 128 + c;
            const float* p1 = xw + (size_t)__shfl(idx_l, t + 1, 64) * 128 + c;
            const float* p2 = xw + (size_t)__shfl(idx_l, t + 2, 64) * 128 + c;
            const float* p3 = xw + (size_t)__shfl(idx_l, t + 3, 64) * 128 + c;
            const float* p4 = xw + (size_t)__shfl(idx_l, t + 4, 64) * 128 + c;
            const float* p5 = xw + (size_t)__shfl(idx_l, t + 5, 64) * 128 + c;
            const float* p6 = xw + (size_t)__shfl(idx_l, t + 6, 64) * 128 + c;
            const float* p7 = xw + (size_t)__shfl(idx_l, t + 7, 64) * 128 + c;
            float2 v0 = *(const float2*)p0;
            float2 v1 = *(const float2*)p1;
            float2 v2 = *(const float2*)p2;
            float2 v3 = *(const float2*)p3;
            float2 v4 = *(const float2*)p4;
            float2 v5 = *(const float2*)p5;
            float2 v6 = *(const float2*)p6;
            float2 v7 = *(const float2*)p7;
            ax += v0.x; ay += v0.y;
            ax += v1.x; ay += v1.y;
            ax += v2.x; ay += v2.y;
            ax += v3.x; ay += v3.y;
            ax += v4.x; ay += v4.y;
            ax += v5.x; ay += v5.y;
            ax += v6.x; ay += v6.y;
            ax += v7.x; ay += v7.y;
        }
        for (; t < cnt_i; ++t) {
            int s = __shfl(idx_l, t, 64);
            float2 v = *(const float2*)(xw + (size_t)s * 128 + c);
            ax += v.x; ay += v.y;
        }
    }
    float di = dinv[node];
    float2 bv = *(const float2*)(bias + c);
    *(float2*)(out + (size_t)node * 128 + c) = make_float2(ax * di + bv.x, ay * di + bv.y);
}

// ---------------- Quantize v6 (MFMA prods + register softmax) ----------------
// grid (ceil(n/128), 4). Block 256 = 4 waves; wave w owns node rows 32w..32w+31
// (2 row-tiles of 16). prods[128 nodes][128 cents(8 pad)] via 16x16x32 bf16
// MFMA, 3-term split: A = h2 hi/lo (LDS [128][72]-short, 2-way-free reads);
// B = cent hi/lo straight from global (123KB, L2-hot), per-ct to cap VGPRs.
// C layout [m89]: cent = lane&15, node = tile*16 + (lane>>4)*4 + reg.
// Softmax per node over group g via per-lane ct-masks + 16-lane masked
// butterflies (exact first-max tie-break). Only 2 __syncthreads total.

__global__ __launch_bounds__(256, 3) void k_quant6(const short* __restrict__ h2h,
                                                   const short* __restrict__ h2l,
                                                   const short* __restrict__ ch,
                                                   const short* __restrict__ cl,
                                                   const float* __restrict__ cent,
                                                   short* __restrict__ h3h,
                                                   short* __restrict__ h3l,
                                                   float* __restrict__ balance_g, int n) {
    __shared__ short Ah[128 * 72];
    __shared__ short Al[128 * 72];
    __shared__ float bal4[4 * 128];
    __shared__ int km_ls[128 * 4];
    const int tid = threadIdx.x;
    const int n0 = blockIdx.x * 128;
    const int d = blockIdx.y;
    const int wave = tid >> 6, lane = tid & 63;
    const int l = lane & 15, lk = lane >> 4;
    const int nib = lane & 48;

    // stage A: h2 hi/lo rows [n0..n0+127], k-slice d*64..+63
    {
        const int row = tid >> 1, half = tid & 1;
        const size_t g = (size_t)(n0 + row) * 256 + d * 64 + half * 32;
        const int o = row * 72 + half * 32;
        const bf16x8 z8 = {0, 0, 0, 0, 0, 0, 0, 0};
        bool v = (n0 + row) < n;
#pragma unroll
        for (int s = 0; s < 4; ++s) {
            *(bf16x8*)&Ah[o + s * 8] = v ? *(const bf16x8*)(h2h + g + s * 8) : z8;
            *(bf16x8*)&Al[o + s * 8] = v ? *(const bf16x8*)(h2l + g + s * 8) : z8;
        }
    }
    __syncthreads();

    // MFMA: acc[t][ct] for t=0,1 row-tiles, ct=0..7 cent-tiles
    f32x4 acc[2][8] = {};
#pragma unroll
    for (int kc = 0; kc < 2; ++kc) {
        bf16x8 ah[2], al[2];
#pragma unroll
        for (int t = 0; t < 2; ++t) {
            int off = (wave * 32 + t * 16 + l) * 72 + kc * 32 + lk * 8;
            ah[t] = *(const bf16x8*)&Ah[off];
            al[t] = *(const bf16x8*)&Al[off];
        }
#pragma unroll
        for (int ct = 0; ct < 8; ++ct) {
            size_t boff = (size_t)(ct * 16 + l) * 256 + d * 64 + kc * 32 + lk * 8;
            bf16x8 bh = *(const bf16x8*)(ch + boff);
            bf16x8 bl = *(const bf16x8*)(cl + boff);
#pragma unroll
            for (int t = 0; t < 2; ++t) {
                acc[t][ct] = __builtin_amdgcn_mfma_f32_16x16x32_bf16(al[t], bh, acc[t][ct], 0, 0, 0);
                acc[t][ct] = __builtin_amdgcn_mfma_f32_16x16x32_bf16(ah[t], bl, acc[t][ct], 0, 0, 0);
                acc[t][ct] = __builtin_amdgcn_mfma_f32_16x16x32_bf16(ah[t], bh, acc[t][ct], 0, 0, 0);
            }
        }
    }

    // per-lane group of each ct (cent = ct*16 + l): g0:<8, g1:<24, g2:<56, g3:<120, -1 pad
    int gof[8];
    gof[0] = (l < 8) ? 0 : 1;
    gof[1] = (l < 8) ? 1 : 2;
    gof[2] = 2;
    gof[3] = (l < 8) ? 2 : 3;
    gof[4] = 3; gof[5] = 3; gof[6] = 3;
    gof[7] = (l < 8) ? 3 : -1;

    float balp[8] = {};

#pragma unroll
    for (int t = 0; t < 2; ++t)
#pragma unroll
        for (int r = 0; r < 4; ++r) {
            const int node = wave * 32 + t * 16 + lk * 4 + r;
            const bool act = (n0 + node) < n;
            float v[8];
#pragma unroll
            for (int ct = 0; ct < 8; ++ct) v[ct] = acc[t][ct][r];

            float mg[4];
            int ag[4];
#pragma unroll
            for (int g = 0; g < 4; ++g) {
                float m = -3.4e38f;
                int am = 0x7FFFFFFF;
#pragma unroll
                for (int ct = 0; ct < 8; ++ct)
                    if (gof[ct] == g && v[ct] > m) { m = v[ct]; am = ct * 16 + l; }
                // masked butterfly over the 16-lane nibble, first-max tie-break
#pragma unroll
                for (int s = 1; s <= 8; s <<= 1) {
                    int srcl = nib | (l ^ s);
                    float mo = __shfl(m, srcl, 64);
                    int amo = __shfl(am, srcl, 64);
                    if (mo > m || (mo == m && amo < am)) { m = mo; am = amo; }
                }
                mg[g] = m;
                ag[g] = am;
            }
            float e[8];
            float Z[4] = {0.f, 0.f, 0.f, 0.f};
#pragma unroll
            for (int ct = 0; ct < 8; ++ct) {
                float ms = (gof[ct] == 0) ? mg[0] : (gof[ct] == 1) ? mg[1]
                         : (gof[ct] == 2) ? mg[2] : mg[3];
                e[ct] = (gof[ct] >= 0) ? expf(v[ct] - ms) : 0.f;
            }
#pragma unroll
            for (int g = 0; g < 4; ++g) {
#pragma unroll
                for (int ct = 0; ct < 8; ++ct)
                    if (gof[ct] == g) Z[g] += e[ct];
#pragma unroll
                for (int s = 1; s <= 8; s <<= 1) {
                    int srcl = nib | (l ^ s);
                    Z[g] += __shfl(Z[g], srcl, 64);
                }
            }
            float iz[4];
#pragma unroll
            for (int g = 0; g < 4; ++g) iz[g] = act ? (1.0f / Z[g]) : 0.f;
#pragma unroll
            for (int ct = 0; ct < 8; ++ct) {
                float s = (gof[ct] == 0) ? iz[0] : (gof[ct] == 1) ? iz[1]
                        : (gof[ct] == 2) ? iz[2] : (gof[ct] == 3) ? iz[3] : 0.f;
                balp[ct] += e[ct] * s;
            }
            if (l == 0) {
#pragma unroll
                for (int g = 0; g < 4; ++g) km_ls[node * 4 + g] = ag[g];
            }
        }

    // balance: reduce over the 4 nibbles (node subsets), store per-wave slice
#pragma unroll
    for (int ct = 0; ct < 8; ++ct) {
        float b = balp[ct];
        b += __shfl_xor(b, 16, 64);
        b += __shfl_xor(b, 32, 64);
        balp[ct] = b;
    }
    if (lane < 16) {
#pragma unroll
        for (int ct = 0; ct < 8; ++ct) bal4[wave * 128 + ct * 16 + l] = balp[ct];
    }
    __syncthreads();
    if (tid < 120) {
        float s = bal4[tid] + bal4[128 + tid] + bal4[256 + tid] + bal4[384 + tid];
        atomicAdd(&balance_g[tid * 4 + d], s);
    }

    // P4: h3 = h2 + max_j cent[km_j]; h2 reconstructed from LDS hi+lo
    {
        const int node = tid >> 1;
        const int half = tid & 1;
        if (n0 + node < n) {
            int k0 = km_ls[node * 4 + 0], k1 = km_ls[node * 4 + 1];
            int k2 = km_ls[node * 4 + 2], k3 = km_ls[node * 4 + 3];
            const float* c0 = cent + (size_t)k0 * 256 + d * 64 + half * 32;
            const float* c1 = cent + (size_t)k1 * 256 + d * 64 + half * 32;
            const float* c2 = cent + (size_t)k2 * 256 + d * 64 + half * 32;
            const float* c3 = cent + (size_t)k3 * 256 + d * 64 + half * 32;
            const int ao = node * 72 + half * 32;
            size_t obase = (size_t)(n0 + node) * 256 + d * 64 + half * 32;
#pragma unroll
            for (int q = 0; q < 8; ++q) {
                int g = q * 4;
                float4 v0 = *(const float4*)(c0 + g);
                float4 v1 = *(const float4*)(c1 + g);
                float4 v2 = *(const float4*)(c2 + g);
                float4 v3 = *(const float4*)(c3 + g);
                float e[4];
#pragma unroll
                for (int u = 0; u < 4; ++u) {
                    float hv = bf16_to_f((unsigned short)Ah[ao + g + u]) +
                               bf16_to_f((unsigned short)Al[ao + g + u]);
                    float m0 = fmaxf(fmaxf(((const float*)&v0)[u], ((const float*)&v1)[u]),
                                     fmaxf(((const float*)&v2)[u], ((const float*)&v3)[u]));
                    e[u] = hv + m0;
                }
                unsigned short h[4], lo[4];
                split4(e, h, lo);
                *(uint2*)(h3h + obase + g) = make_uint2(h[0] | (h[1] << 16), h[2] | (h[3] << 16));
                *(uint2*)(h3l + obase + g) = make_uint2(lo[0] | (lo[1] << 16), lo[2] | (lo[3] << 16));
            }
        }
    }
}

__global__ void k_reg(const float* __restrict__ balance_g, float* __restrict__ out_reg,
                      float inv_n) {
    __shared__ float red[512];
    int tid = threadIdx.x;
    float v = 0.f;
    if (tid < 480) {
        int k = tid >> 2;
        float target = (k < 8) ? 0.125f : (k < 24) ? 0.0625f : (k < 56) ? 0.03125f : 0.015625f;
        float b = balance_g[tid] * inv_n;
        float df = b - target;
        v = df * df;
    }
    red[tid] = v;
    __syncthreads();
    for (int s = 256; s > 0; s >>= 1) {
        if (tid < s) red[tid] += red[tid + s];
        __syncthreads();
    }
    if (tid == 0) *out_reg = sqrtf(red[0]);
}

// ---------------- host launch ----------------

extern "C" void kernel_launch(void* const* d_in, const int* in_sizes, int n_in,
                              void* d_out, int out_size, void* d_ws, size_t ws_size,
                              hipStream_t stream) {
    const float* x    = (const float*)d_in[0];
    const int*   ei   = (const int*)d_in[1];
    const float* W0   = (const float*)d_in[2];
    const float* b0   = (const float*)d_in[3];
    const float* W1   = (const float*)d_in[4];
    const float* b1   = (const float*)d_in[5];
    const float* W2   = (const float*)d_in[6];
    const float* b2   = (const float*)d_in[7];
    const float* cent = (const float*)d_in[8];
    const int n = in_sizes[0] / 256;
    const int e = in_sizes[1] / 2;
    const int* src = ei;
    const int* dst = ei + e;
    float* out = (float*)d_out;

    char* w = (char*)d_ws;
    float* bufA = (float*)w;      w += (size_t)n * 256 * 4;
    float* bufB = (float*)w;      w += (size_t)n * 256 * 4;
    float* dinv = (float*)w;      w += (size_t)n * 4;
    int* cnt = (int*)w;           w += (size_t)n * 4;
    int* row_start = (int*)w;     w += (size_t)n * 4;
    int* cursor = (int*)w;        w += (size_t)n * 4;
    int* csr_src = (int*)w;       w += (size_t)e * 4;
    int* counter = (int*)w;       w += 256;
    float* balance = (float*)w;   w += 480 * 4;
    short* w0h = (short*)w;       w += 256 * 256 * 2;
    short* w0l = (short*)w;       w += 256 * 256 * 2;
    short* w1h = (short*)w;       w += 256 * 256 * 2;
    short* w1l = (short*)w;       w += 256 * 256 * 2;
    short* w2h = (short*)w;       w += 128 * 256 * 2;
    short* w2l = (short*)w;       w += 128 * 256 * 2;
    short* ch  = (short*)w;       w += 128 * 256 * 2;
    short* cl  = (short*)w;       w += 128 * 256 * 2;

    // buffer roles:
    //   splitA : x -> bufA = [Xh | Xl]
    //   gemm1  : bufA -> bufB fp32 (xws1, dinv-scaled)
    //   agg4#1 : bufB -> bufA = [H1h | H1l]
    //   gemm2  : bufA -> bufB fp32 (xws2, dinv-scaled)
    //   agg4#2 : bufB -> bufA = [H2h | H2l]
    //   quant6 : bufA(+cent splits) -> bufB = [H3h | H3l], balance
    //   gemm3  : bufB -> bufA fp32 (xws3, 128-dim, dinv-scaled)
    //   agg2   : bufA -> out
    short* xh = (short*)bufA;
    short* xl = xh + (size_t)n * 256;
    short* h1h = (short*)bufA;
    short* h1l = h1h + (size_t)n * 256;
    short* h2h = (short*)bufA;
    short* h2l = h2h + (size_t)n * 256;
    short* h3h = (short*)bufB;
    short* h3l = h3h + (size_t)n * 256;

    const int tb = 256;
    k_init<<<(n + tb - 1) / tb, tb, 0, stream>>>(cnt, cursor, counter, balance, n);
    k_count<<<(e + tb - 1) / tb, tb, 0, stream>>>(dst, cnt, e);
    k_allocdinv<<<(n + tb - 1) / tb, tb, 0, stream>>>(cnt, row_start, counter, dinv, n);
    k_fill<<<(e + tb - 1) / tb, tb, 0, stream>>>(src, dst, row_start, cursor, csr_src, e);

    k_splitWC<<<196608 / tb, tb, 0, stream>>>(W0, W1, W2, cent, w0h, w0l, w1h, w1l,
                                              w2h, w2l, ch, cl);
    k_splitA<<<(n * 32 + tb - 1) / tb, tb, 0, stream>>>(x, xh, xl, n * 32);

    dim3 g1((n + 127) / 128, 2);
    k_gemm_bf16s<<<g1, 256, 0, stream>>>(xh, xl, w0h, w0l, dinv, bufB, n, 256);
    k_agg4<true, 1><<<(n + 3) / 4, 256, 0, stream>>>(bufB, dinv, csr_src, row_start,
                                                     cnt, b0, nullptr, h1h, h1l, n);
    k_gemm_bf16s<<<g1, 256, 0, stream>>>(h1h, h1l, w1h, w1l, dinv, bufB, n, 256);
    k_agg4<true, 1><<<(n + 3) / 4, 256, 0, stream>>>(bufB, dinv, csr_src, row_start,
                                                     cnt, b1, nullptr, h2h, h2l, n);

    dim3 gq((n + 127) / 128, 4);
    k_quant6<<<gq, 256, 0, stream>>>(h2h, h2l, ch, cl, cent, h3h, h3l, balance, n);

    dim3 g3((n + 127) / 128, 1);
    k_gemm_bf16s<<<g3, 256, 0, stream>>>(h3h, h3l, w2h, w2l, dinv, bufA, n, 128);
    k_agg2<<<(n + 3) / 4, 256, 0, stream>>>(bufA, dinv, csr_src, row_start,
                                            cnt, b2, out, n);
    k_reg<<<1, 512, 0, stream>>>(balance, out + (size_t)n * 128, 1.0f / (float)n);
}

// Round 11
// 634.680 us; speedup vs baseline: 1.0273x; 1.0273x over previous
//
#include <hip/hip_runtime.h>
#include <math.h>

// ---------------------------------------------------------------------------
// GCN pipeline: conv1(relu) -> conv2(relu) -> quantize(+reg) -> add -> conv3
// GEMMs + quantize-prods: split-bf16 MFMA (Ootomo 3-term), pre-split tables.
// Norm folding: gemm epilogue scales row r by dinv[r]; aggregation is pure
// gather-sum * dinv[node] + bias (csr_norm eliminated).
// quant v7: mfma(A=cent, B=h2) -> node on lane&15 -> softmax is lane-local
// (T12 swapped-operand trick; round-10's cent-on-lane layout was the bug).
// ---------------------------------------------------------------------------

typedef short bf16x8 __attribute__((ext_vector_type(8)));
typedef float f32x4 __attribute__((ext_vector_type(4)));

__device__ __forceinline__ unsigned short bf16_rne(float a) {
    unsigned u = __builtin_bit_cast(unsigned, a);
    return (unsigned short)((u + 0x7FFFu + ((u >> 16) & 1u)) >> 16);
}
__device__ __forceinline__ float bf16_to_f(unsigned short h) {
    return __builtin_bit_cast(float, (unsigned)h << 16);
}
__device__ __forceinline__ void split4(const float* e, unsigned short* h, unsigned short* l) {
#pragma unroll
    for (int t = 0; t < 4; ++t) {
        h[t] = bf16_rne(e[t]);
        l[t] = bf16_rne(e[t] - bf16_to_f(h[t]));
    }
}

// ---------------- CSR build ----------------

__global__ void k_init(int* cnt, int* cursor, int* counter, float* balance, int n) {
    int i = blockIdx.x * blockDim.x + threadIdx.x;
    if (i < n) { cnt[i] = 0; cursor[i] = 0; }
    if (i < 480) balance[i] = 0.f;
    if (i == 0) *counter = 0;
}

__global__ void k_count(const int* __restrict__ dst, int* __restrict__ cnt, int e) {
    int i = blockIdx.x * blockDim.x + threadIdx.x;
    if (i < e) atomicAdd(&cnt[dst[i]], 1);
}

__global__ void k_allocdinv(const int* __restrict__ cnt, int* __restrict__ row_start,
                            int* __restrict__ counter, float* __restrict__ dinv, int n) {
    int i = blockIdx.x * blockDim.x + threadIdx.x;
    if (i < n) {
        row_start[i] = atomicAdd(counter, cnt[i]);
        dinv[i] = rsqrtf((float)cnt[i] + 1.0f);   // +1 self loop
    }
}

__global__ void k_fill(const int* __restrict__ src, const int* __restrict__ dst,
                       const int* __restrict__ row_start, int* __restrict__ cursor,
                       int* __restrict__ csr_src, int e) {
    int i = blockIdx.x * blockDim.x + threadIdx.x;
    if (i >= e) return;
    int s = src[i], d = dst[i];
    int slot = atomicAdd(&cursor[d], 1);
    csr_src[row_start[d] + slot] = s;
}

// ---------------- split kernels ----------------

__global__ void k_splitWC(const float* __restrict__ W0, const float* __restrict__ W1,
                          const float* __restrict__ W2, const float* __restrict__ cent,
                          short* __restrict__ w0h, short* __restrict__ w0l,
                          short* __restrict__ w1h, short* __restrict__ w1l,
                          short* __restrict__ w2h, short* __restrict__ w2l,
                          short* __restrict__ ch, short* __restrict__ cl) {
    int i = blockIdx.x * blockDim.x + threadIdx.x;
    float v;
    short *ph, *pl;
    int j;
    if (i < 65536) {
        j = i; v = W0[(j & 255) * 256 + (j >> 8)]; ph = w0h; pl = w0l;
    } else if (i < 131072) {
        j = i - 65536; v = W1[(j & 255) * 256 + (j >> 8)]; ph = w1h; pl = w1l;
    } else if (i < 163840) {
        j = i - 131072; v = W2[(j & 255) * 128 + (j >> 8)]; ph = w2h; pl = w2l;
    } else {
        j = i - 163840; int c = j >> 8;
        v = (c < 120) ? cent[j] : 0.f; ph = ch; pl = cl;
    }
    unsigned short h = bf16_rne(v);
    ph[j] = (short)h;
    pl[j] = (short)bf16_rne(v - bf16_to_f(h));
}

__global__ void k_splitA(const float* __restrict__ X, short* __restrict__ Hi,
                         short* __restrict__ Lo, int total8) {
    int i = blockIdx.x * blockDim.x + threadIdx.x;
    if (i >= total8) return;
    float4 a = *(const float4*)(X + (size_t)i * 8);
    float4 b = *(const float4*)(X + (size_t)i * 8 + 4);
    float e0[4] = {a.x, a.y, a.z, a.w}, e1[4] = {b.x, b.y, b.z, b.w};
    unsigned short h0[4], l0[4], h1[4], l1[4];
    split4(e0, h0, l0);
    split4(e1, h1, l1);
    *(uint4*)(Hi + (size_t)i * 8) = make_uint4(h0[0] | (h0[1] << 16), h0[2] | (h0[3] << 16),
                                              h1[0] | (h1[1] << 16), h1[2] | (h1[3] << 16));
    *(uint4*)(Lo + (size_t)i * 8) = make_uint4(l0[0] | (l0[1] << 16), l0[2] | (l0[3] << 16),
                                              l1[0] | (l1[1] << 16), l1[2] | (l1[3] << 16));
}

// ---------------- bf16-split MFMA GEMM (dinv-scaled epilogue) ----------------

__global__ __launch_bounds__(256, 2) void k_gemm_bf16s(const short* __restrict__ Ah,
                                                       const short* __restrict__ Al,
                                                       const short* __restrict__ Bh,
                                                       const short* __restrict__ Bl,
                                                       const float* __restrict__ dinv,
                                                       float* __restrict__ C,
                                                       int M, int N) {
    __shared__ short smem[4 * 128 * 56];
    short* Ash = smem;
    short* Asl = smem + 7168;
    short* Bsh = smem + 14336;
    short* Bsl = smem + 21504;
    const int tid = threadIdx.x;
    const int bm = blockIdx.x * 128;
    const int bn = blockIdx.y * 128;
    const int wave = tid >> 6, lane = tid & 63;
    const int wr = wave >> 1, wc = wave & 1;
    const int lr = lane & 15, lk = lane >> 4;

    int srow[2], ssg[2];
    bool aval[2];
#pragma unroll
    for (int it = 0; it < 2; ++it) {
        int u = it * 256 + tid;
        srow[it] = u >> 2;
        ssg[it] = (u & 3) << 3;
        aval[it] = (bm + srow[it]) < M;
    }

    const bf16x8 z8 = {0, 0, 0, 0, 0, 0, 0, 0};
    bf16x8 pah[2], pal[2], pbh[2], pbl[2];

    auto prefetch = [&](int k0) {
#pragma unroll
        for (int it = 0; it < 2; ++it) {
            size_t arow = (size_t)(bm + srow[it]) * 256 + k0 + ssg[it];
            size_t brow = (size_t)(bn + srow[it]) * 256 + k0 + ssg[it];
            pah[it] = aval[it] ? *(const bf16x8*)(Ah + arow) : z8;
            pal[it] = aval[it] ? *(const bf16x8*)(Al + arow) : z8;
            pbh[it] = *(const bf16x8*)(Bh + brow);
            pbl[it] = *(const bf16x8*)(Bl + brow);
        }
    };

    f32x4 acc[4][4] = {};
    prefetch(0);

    for (int k0 = 0; k0 < 256; k0 += 32) {
#pragma unroll
        for (int it = 0; it < 2; ++it) {
            int off = srow[it] * 56 + ssg[it];
            *(bf16x8*)&Ash[off] = pah[it];
            *(bf16x8*)&Asl[off] = pal[it];
            *(bf16x8*)&Bsh[off] = pbh[it];
            *(bf16x8*)&Bsl[off] = pbl[it];
        }
        __syncthreads();

        bf16x8 ah[4], al[4], bh[4], bl[4];
#pragma unroll
        for (int i = 0; i < 4; ++i) {
            int off = (wr * 64 + i * 16 + lr) * 56 + lk * 8;
            ah[i] = *(bf16x8*)&Ash[off];
            al[i] = *(bf16x8*)&Asl[off];
        }
#pragma unroll
        for (int j = 0; j < 4; ++j) {
            int off = (wc * 64 + j * 16 + lr) * 56 + lk * 8;
            bh[j] = *(bf16x8*)&Bsh[off];
            bl[j] = *(bf16x8*)&Bsl[off];
        }

        if (k0 < 224) prefetch(k0 + 32);

#pragma unroll
        for (int i = 0; i < 4; ++i)
#pragma unroll
            for (int j = 0; j < 4; ++j) {
                acc[i][j] = __builtin_amdgcn_mfma_f32_16x16x32_bf16(al[i], bh[j], acc[i][j], 0, 0, 0);
                acc[i][j] = __builtin_amdgcn_mfma_f32_16x16x32_bf16(ah[i], bl[j], acc[i][j], 0, 0, 0);
                acc[i][j] = __builtin_amdgcn_mfma_f32_16x16x32_bf16(ah[i], bh[j], acc[i][j], 0, 0, 0);
            }
        __syncthreads();
    }

    float* Cs = (float*)smem;
#pragma unroll
    for (int p = 0; p < 2; ++p) {
        if (wc == p) {
#pragma unroll
            for (int i = 0; i < 4; ++i)
#pragma unroll
                for (int r = 0; r < 4; ++r) {
                    int row = wr * 64 + i * 16 + lk * 4 + r;
#pragma unroll
                    for (int j = 0; j < 4; ++j)
                        Cs[row * 68 + j * 16 + lr] = acc[i][j][r];
                }
        }
        __syncthreads();
#pragma unroll
        for (int t = 0; t < 8; ++t) {
            int idx = t * 256 + tid;
            int row = idx >> 4, c4 = idx & 15;
            if (bm + row < M) {
                float s = dinv[bm + row];
                float4 v = *(const float4*)&Cs[row * 68 + c4 * 4];
                v.x *= s; v.y *= s; v.z *= s; v.w *= s;
                *(float4*)(C + (size_t)(bm + row) * N + bn + p * 64 + c4 * 4) = v;
            }
        }
        __syncthreads();
    }
}

// ---------------- Aggregation (pure gather-sum over CSR) ----------------

template <bool RELU, int MODE>
__global__ __launch_bounds__(256, 4) void k_agg4(const float* __restrict__ xw,
                                                 const float* __restrict__ dinv,
                                                 const int* __restrict__ csr_src,
                                                 const int* __restrict__ row_start,
                                                 const int* __restrict__ cnt,
                                                 const float* __restrict__ bias,
                                                 float* __restrict__ out,
                                                 short* __restrict__ outH,
                                                 short* __restrict__ outL, int n) {
    int node = blockIdx.x * 4 + (threadIdx.x >> 6);
    if (node >= n) return;
    int lane = threadIdx.x & 63;
    int c = lane * 4;
    float4 self = *(const float4*)(xw + (size_t)node * 256 + c);
    float ax = self.x, ay = self.y, az = self.z, aw = self.w;
    int st = row_start[node];
    int m = cnt[node];
    for (int t0 = 0; t0 < m; t0 += 64) {
        int rem = m - t0;
        int cnt_i = rem < 64 ? rem : 64;
        int idx_l = 0;
        if (lane < cnt_i) idx_l = csr_src[st + t0 + lane];
        int t = 0;
        for (; t + 8 <= cnt_i; t += 8) {
            const float* p0 = xw + (size_t)__shfl(idx_l, t + 0, 64) * 256 + c;
            const float* p1 = xw + (size_t)__shfl(idx_l, t + 1, 64) * 256 + c;
            const float* p2 = xw + (size_t)__shfl(idx_l, t + 2, 64) * 256 + c;
            const float* p3 = xw + (size_t)__shfl(idx_l, t + 3, 64) * 256 + c;
            const float* p4 = xw + (size_t)__shfl(idx_l, t + 4, 64) * 256 + c;
            const float* p5 = xw + (size_t)__shfl(idx_l, t + 5, 64) * 256 + c;
            const float* p6 = xw + (size_t)__shfl(idx_l, t + 6, 64) * 256 + c;
            const float* p7 = xw + (size_t)__shfl(idx_l, t + 7, 64) * 256 + c;
            float4 v0 = *(const float4*)p0;
            float4 v1 = *(const float4*)p1;
            float4 v2 = *(const float4*)p2;
            float4 v3 = *(const float4*)p3;
            float4 v4 = *(const float4*)p4;
            float4 v5 = *(const float4*)p5;
            float4 v6 = *(const float4*)p6;
            float4 v7 = *(const float4*)p7;
            ax += v0.x; ay += v0.y; az += v0.z; aw += v0.w;
            ax += v1.x; ay += v1.y; az += v1.z; aw += v1.w;
            ax += v2.x; ay += v2.y; az += v2.z; aw += v2.w;
            ax += v3.x; ay += v3.y; az += v3.z; aw += v3.w;
            ax += v4.x; ay += v4.y; az += v4.z; aw += v4.w;
            ax += v5.x; ay += v5.y; az += v5.z; aw += v5.w;
            ax += v6.x; ay += v6.y; az += v6.z; aw += v6.w;
            ax += v7.x; ay += v7.y; az += v7.z; aw += v7.w;
        }
        for (; t < cnt_i; ++t) {
            int s = __shfl(idx_l, t, 64);
            float4 v = *(const float4*)(xw + (size_t)s * 256 + c);
            ax += v.x; ay += v.y; az += v.z; aw += v.w;
        }
    }
    float di = dinv[node];
    float4 bv = *(const float4*)(bias + c);
    ax = ax * di + bv.x;
    ay = ay * di + bv.y;
    az = az * di + bv.z;
    aw = aw * di + bv.w;
    if (RELU) {
        ax = ax > 0.f ? ax : 0.5f * ax;
        ay = ay > 0.f ? ay : 0.5f * ay;
        az = az > 0.f ? az : 0.5f * az;
        aw = aw > 0.f ? aw : 0.5f * aw;
    }
    if (MODE == 0) {
        *(float4*)(out + (size_t)node * 256 + c) = make_float4(ax, ay, az, aw);
    } else {
        float e[4] = {ax, ay, az, aw};
        unsigned short h[4], l[4];
        split4(e, h, l);
        size_t o = (size_t)node * 256 + c;
        *(uint2*)(outH + o) = make_uint2(h[0] | (h[1] << 16), h[2] | (h[3] << 16));
        *(uint2*)(outL + o) = make_uint2(l[0] | (l[1] << 16), l[2] | (l[3] << 16));
    }
}

__global__ __launch_bounds__(256, 4) void k_agg2(const float* __restrict__ xw,
                                                 const float* __restrict__ dinv,
                                                 const int* __restrict__ csr_src,
                                                 const int* __restrict__ row_start,
                                                 const int* __restrict__ cnt,
                                                 const float* __restrict__ bias,
                                                 float* __restrict__ out, int n) {
    int node = blockIdx.x * 4 + (threadIdx.x >> 6);
    if (node >= n) return;
    int lane = threadIdx.x & 63;
    int c = lane * 2;
    float2 self = *(const float2*)(xw + (size_t)node * 128 + c);
    float ax = self.x, ay = self.y;
    int st = row_start[node];
    int m = cnt[node];
    for (int t0 = 0; t0 < m; t0 += 64) {
        int rem = m - t0;
        int cnt_i = rem < 64 ? rem : 64;
        int idx_l = 0;
        if (lane < cnt_i) idx_l = csr_src[st + t0 + lane];
        int t = 0;
        for (; t + 8 <= cnt_i; t += 8) {
            const float* p0 = xw + (size_t)__shfl(idx_l, t + 0, 64) * 128 + c;
            const float* p1 = xw + (size_t)__shfl(idx_l, t + 1, 64) * 128 + c;
            const float* p2 = xw + (size_t)__shfl(idx_l, t + 2, 64) * 128 + c;
            const float* p3 = xw + (size_t)__shfl(idx_l, t + 3, 64) * 128 + c;
            const float* p4 = xw + (size_t)__shfl(idx_l, t + 4, 64) * 128 + c;
            const float* p5 = xw + (size_t)__shfl(idx_l, t + 5, 64) * 128 + c;
            const float* p6 = xw + (size_t)__shfl(idx_l, t + 6, 64) * 128 + c;
            const float* p7 = xw + (size_t)__shfl(idx_l, t + 7, 64) * 128 + c;
            float2 v0 = *(const float2*)p0;
            float2 v1 = *(const float2*)p1;
            float2 v2 = *(const float2*)p2;
            float2 v3 = *(const float2*)p3;
            float2 v4 = *(const float2*)p4;
            float2 v5 = *(const float2*)p5;
            float2 v6 = *(const float2*)p6;
            float2 v7 = *(const float2*)p7;
            ax += v0.x; ay += v0.y;
            ax += v1.x; ay += v1.y;
            ax += v2.x; ay += v2.y;
            ax += v3.x; ay += v3.y;
            ax += v4.x; ay += v4.y;
            ax += v5.x; ay += v5.y;
            ax += v6.x; ay += v6.y;
            ax += v7.x; ay += v7.y;
        }
        for (; t < cnt_i; ++t) {
            int s = __shfl(idx_l, t, 64);
            float2 v = *(const float2*)(xw + (size_t)s * 128 + c);
            ax += v.x; ay += v.y;
        }
    }
    float di = dinv[node];
    float2 bv = *(const float2*)(bias + c);
    *(float2*)(out + (size_t)node * 128 + c) = make_float2(ax * di + bv.x, ay * di + bv.y);
}

// ---------------- Quantize v7 (swapped-operand MFMA, lane-local softmax) ----
// mfma(A=cent, B=h2): D[cent][node], node = lane&15, cent = ct*16 + lk*4 + r.
// Each lane owns one node's full prods slice -> softmax is in-lane + 2-step
// lk-butterflies. Group of cent depends only on (ct, lk>=2): 2 static arms
// (boundaries 8/24/56/120 are half-tile-aligned); shfls kept OUTSIDE arms.

#define Q7_UPDMAX(MG, AG, NT, CT)                               \
    {                                                           \
        _Pragma("unroll")                                       \
        for (int r = 0; r < 4; ++r) {                           \
            float v = acc[NT][CT][r];                           \
            int cid = (CT) * 16 + lk4 + r;                      \
            if (v > MG) { MG = v; AG = cid; }                   \
        }                                                       \
    }
#define Q7_BFLY(MG, AG)                                         \
    {                                                           \
        float mo16 = __shfl_xor(MG, 16, 64);                    \
        int ao16 = __shfl_xor(AG, 16, 64);                      \
        if (mo16 > MG || (mo16 == MG && ao16 < AG)) { MG = mo16; AG = ao16; } \
        float mo32 = __shfl_xor(MG, 32, 64);                    \
        int ao32 = __shfl_xor(AG, 32, 64);                      \
        if (mo32 > MG || (mo32 == MG && ao32 < AG)) { MG = mo32; AG = ao32; } \
    }
#define Q7_EXPZ(MG, ZG, NT, CT)                                 \
    {                                                           \
        _Pragma("unroll")                                       \
        for (int r = 0; r < 4; ++r) {                           \
            float e2 = expf(acc[NT][CT][r] - MG);               \
            acc[NT][CT][r] = e2;                                \
            ZG += e2;                                           \
        }                                                       \
    }
#define Q7_ZBF(ZG)                                              \
    { ZG += __shfl_xor(ZG, 16, 64); ZG += __shfl_xor(ZG, 32, 64); }
#define Q7_BAL(IZ, NT, CT)                                      \
    {                                                           \
        _Pragma("unroll")                                       \
        for (int r = 0; r < 4; ++r) balp[CT][r] += acc[NT][CT][r] * IZ; \
    }

__global__ __launch_bounds__(256, 3) void k_quant7(const short* __restrict__ h2h,
                                                   const short* __restrict__ h2l,
                                                   const short* __restrict__ ch,
                                                   const short* __restrict__ cl,
                                                   const float* __restrict__ cent,
                                                   short* __restrict__ h3h,
                                                   short* __restrict__ h3l,
                                                   float* __restrict__ balance_g, int n) {
    __shared__ short Ah[128 * 72];
    __shared__ short Al[128 * 72];
    __shared__ float bal4[4 * 128];
    __shared__ int km_ls[128 * 4];
    const int tid = threadIdx.x;
    const int n0 = blockIdx.x * 128;
    const int d = blockIdx.y;
    const int wave = tid >> 6, lane = tid & 63;
    const int l = lane & 15, lk = lane >> 4;
    const int lk4 = lk * 4;
    const int lkh = lk >> 1;

    // stage h2 hi/lo rows [n0..n0+127], k-slice d*64..+63
    {
        const int row = tid >> 1, half = tid & 1;
        const size_t g = (size_t)(n0 + row) * 256 + d * 64 + half * 32;
        const int o = row * 72 + half * 32;
        const bf16x8 z8 = {0, 0, 0, 0, 0, 0, 0, 0};
        bool v = (n0 + row) < n;
#pragma unroll
        for (int s = 0; s < 4; ++s) {
            *(bf16x8*)&Ah[o + s * 8] = v ? *(const bf16x8*)(h2h + g + s * 8) : z8;
            *(bf16x8*)&Al[o + s * 8] = v ? *(const bf16x8*)(h2l + g + s * 8) : z8;
        }
    }
    __syncthreads();

    // MFMA: acc[nt][ct]; wave handles nodes [wave*32, wave*32+32) as 2 tiles
    f32x4 acc[2][8] = {};
#pragma unroll
    for (int kc = 0; kc < 2; ++kc) {
        bf16x8 nbh[2], nbl[2];
#pragma unroll
        for (int nt = 0; nt < 2; ++nt) {
            int off = (wave * 32 + nt * 16 + l) * 72 + kc * 32 + lk * 8;
            nbh[nt] = *(const bf16x8*)&Ah[off];
            nbl[nt] = *(const bf16x8*)&Al[off];
        }
#pragma unroll
        for (int ct = 0; ct < 8; ++ct) {
            size_t boff = (size_t)(ct * 16 + l) * 256 + d * 64 + kc * 32 + lk * 8;
            bf16x8 cbh = *(const bf16x8*)(ch + boff);
            bf16x8 cbl = *(const bf16x8*)(cl + boff);
#pragma unroll
            for (int nt = 0; nt < 2; ++nt) {
                acc[nt][ct] = __builtin_amdgcn_mfma_f32_16x16x32_bf16(cbl, nbh[nt], acc[nt][ct], 0, 0, 0);
                acc[nt][ct] = __builtin_amdgcn_mfma_f32_16x16x32_bf16(cbh, nbl[nt], acc[nt][ct], 0, 0, 0);
                acc[nt][ct] = __builtin_amdgcn_mfma_f32_16x16x32_bf16(cbh, nbh[nt], acc[nt][ct], 0, 0, 0);
            }
        }
    }

    float balp[8][4] = {};

#pragma unroll
    for (int nt = 0; nt < 2; ++nt) {
        const int node = wave * 32 + nt * 16 + l;
        const bool act = (n0 + node) < n;

        float mg0 = -3.4e38f, mg1 = -3.4e38f, mg2 = -3.4e38f, mg3 = -3.4e38f;
        int ag0 = 0x7FFFFFFF, ag1 = 0x7FFFFFFF, ag2 = 0x7FFFFFFF, ag3 = 0x7FFFFFFF;
        // in-lane partial max/argmax (static per lkh arm; no shfl inside)
        if (lkh == 0) {
            Q7_UPDMAX(mg0, ag0, nt, 0);
            Q7_UPDMAX(mg1, ag1, nt, 1);
            Q7_UPDMAX(mg2, ag2, nt, 2); Q7_UPDMAX(mg2, ag2, nt, 3);
            Q7_UPDMAX(mg3, ag3, nt, 4); Q7_UPDMAX(mg3, ag3, nt, 5);
            Q7_UPDMAX(mg3, ag3, nt, 6); Q7_UPDMAX(mg3, ag3, nt, 7);
        } else {
            Q7_UPDMAX(mg1, ag1, nt, 0);
            Q7_UPDMAX(mg2, ag2, nt, 1); Q7_UPDMAX(mg2, ag2, nt, 2);
            Q7_UPDMAX(mg3, ag3, nt, 3); Q7_UPDMAX(mg3, ag3, nt, 4);
            Q7_UPDMAX(mg3, ag3, nt, 5); Q7_UPDMAX(mg3, ag3, nt, 6);
            // ct7 (cents 120..127) is pad for lkh==1
        }
        // uniform butterflies over lk
        Q7_BFLY(mg0, ag0); Q7_BFLY(mg1, ag1); Q7_BFLY(mg2, ag2); Q7_BFLY(mg3, ag3);

        float zg0 = 0.f, zg1 = 0.f, zg2 = 0.f, zg3 = 0.f;
        if (lkh == 0) {
            Q7_EXPZ(mg0, zg0, nt, 0);
            Q7_EXPZ(mg1, zg1, nt, 1);
            Q7_EXPZ(mg2, zg2, nt, 2); Q7_EXPZ(mg2, zg2, nt, 3);
            Q7_EXPZ(mg3, zg3, nt, 4); Q7_EXPZ(mg3, zg3, nt, 5);
            Q7_EXPZ(mg3, zg3, nt, 6); Q7_EXPZ(mg3, zg3, nt, 7);
        } else {
            Q7_EXPZ(mg1, zg1, nt, 0);
            Q7_EXPZ(mg2, zg2, nt, 1); Q7_EXPZ(mg2, zg2, nt, 2);
            Q7_EXPZ(mg3, zg3, nt, 3); Q7_EXPZ(mg3, zg3, nt, 4);
            Q7_EXPZ(mg3, zg3, nt, 5); Q7_EXPZ(mg3, zg3, nt, 6);
        }
        Q7_ZBF(zg0); Q7_ZBF(zg1); Q7_ZBF(zg2); Q7_ZBF(zg3);

        float iz0 = act ? (1.0f / zg0) : 0.f;
        float iz1 = act ? (1.0f / zg1) : 0.f;
        float iz2 = act ? (1.0f / zg2) : 0.f;
        float iz3 = act ? (1.0f / zg3) : 0.f;
        if (lkh == 0) {
            Q7_BAL(iz0, nt, 0);
            Q7_BAL(iz1, nt, 1);
            Q7_BAL(iz2, nt, 2); Q7_BAL(iz2, nt, 3);
            Q7_BAL(iz3, nt, 4); Q7_BAL(iz3, nt, 5);
            Q7_BAL(iz3, nt, 6); Q7_BAL(iz3, nt, 7);
        } else {
            Q7_BAL(iz1, nt, 0);
            Q7_BAL(iz2, nt, 1); Q7_BAL(iz2, nt, 2);
            Q7_BAL(iz3, nt, 3); Q7_BAL(iz3, nt, 4);
            Q7_BAL(iz3, nt, 5); Q7_BAL(iz3, nt, 6);
        }
        if (lk == 0) {
            km_ls[node * 4 + 0] = ag0;
            km_ls[node * 4 + 1] = ag1;
            km_ls[node * 4 + 2] = ag2;
            km_ls[node * 4 + 3] = ag3;
        }
    }

    // balance: reduce over the 16 node-lanes (l), write per-wave slice
#pragma unroll
    for (int ct = 0; ct < 8; ++ct)
#pragma unroll
        for (int r = 0; r < 4; ++r) {
            float b = balp[ct][r];
            b += __shfl_xor(b, 1, 64);
            b += __shfl_xor(b, 2, 64);
            b += __shfl_xor(b, 4, 64);
            b += __shfl_xor(b, 8, 64);
            if (l == 0) bal4[wave * 128 + ct * 16 + lk4 + r] = b;
        }
    __syncthreads();
    if (tid < 120) {
        float s = bal4[tid] + bal4[128 + tid] + bal4[256 + tid] + bal4[384 + tid];
        atomicAdd(&balance_g[tid * 4 + d], s);
    }

    // P4: h3 = h2 + max_j cent[km_j]; h2 reconstructed from LDS hi+lo
    {
        const int node = tid >> 1;
        const int half = tid & 1;
        if (n0 + node < n) {
            int k0 = km_ls[node * 4 + 0], k1 = km_ls[node * 4 + 1];
            int k2 = km_ls[node * 4 + 2], k3 = km_ls[node * 4 + 3];
            const float* c0 = cent + (size_t)k0 * 256 + d * 64 + half * 32;
            const float* c1 = cent + (size_t)k1 * 256 + d * 64 + half * 32;
            const float* c2 = cent + (size_t)k2 * 256 + d * 64 + half * 32;
            const float* c3 = cent + (size_t)k3 * 256 + d * 64 + half * 32;
            const int ao = node * 72 + half * 32;
            size_t obase = (size_t)(n0 + node) * 256 + d * 64 + half * 32;
#pragma unroll
            for (int q = 0; q < 8; ++q) {
                int g = q * 4;
                float4 v0 = *(const float4*)(c0 + g);
                float4 v1 = *(const float4*)(c1 + g);
                float4 v2 = *(const float4*)(c2 + g);
                float4 v3 = *(const float4*)(c3 + g);
                float e[4];
#pragma unroll
                for (int u = 0; u < 4; ++u) {
                    float hv = bf16_to_f((unsigned short)Ah[ao + g + u]) +
                               bf16_to_f((unsigned short)Al[ao + g + u]);
                    float m0 = fmaxf(fmaxf(((const float*)&v0)[u], ((const float*)&v1)[u]),
                                     fmaxf(((const float*)&v2)[u], ((const float*)&v3)[u]));
                    e[u] = hv + m0;
                }
                unsigned short h[4], lo[4];
                split4(e, h, lo);
                *(uint2*)(h3h + obase + g) = make_uint2(h[0] | (h[1] << 16), h[2] | (h[3] << 16));
                *(uint2*)(h3l + obase + g) = make_uint2(lo[0] | (lo[1] << 16), lo[2] | (lo[3] << 16));
            }
        }
    }
}

__global__ void k_reg(const float* __restrict__ balance_g, float* __restrict__ out_reg,
                      float inv_n) {
    __shared__ float red[512];
    int tid = threadIdx.x;
    float v = 0.f;
    if (tid < 480) {
        int k = tid >> 2;
        float target = (k < 8) ? 0.125f : (k < 24) ? 0.0625f : (k < 56) ? 0.03125f : 0.015625f;
        float b = balance_g[tid] * inv_n;
        float df = b - target;
        v = df * df;
    }
    red[tid] = v;
    __syncthreads();
    for (int s = 256; s > 0; s >>= 1) {
        if (tid < s) red[tid] += red[tid + s];
        __syncthreads();
    }
    if (tid == 0) *out_reg = sqrtf(red[0]);
}

// ---------------- host launch ----------------

extern "C" void kernel_launch(void* const* d_in, const int* in_sizes, int n_in,
                              void* d_out, int out_size, void* d_ws, size_t ws_size,
                              hipStream_t stream) {
    const float* x    = (const float*)d_in[0];
    const int*   ei   = (const int*)d_in[1];
    const float* W0   = (const float*)d_in[2];
    const float* b0   = (const float*)d_in[3];
    const float* W1   = (const float*)d_in[4];
    const float* b1   = (const float*)d_in[5];
    const float* W2   = (const float*)d_in[6];
    const float* b2   = (const float*)d_in[7];
    const float* cent = (const float*)d_in[8];
    const int n = in_sizes[0] / 256;
    const int e = in_sizes[1] / 2;
    const int* src = ei;
    const int* dst = ei + e;
    float* out = (float*)d_out;

    char* w = (char*)d_ws;
    float* bufA = (float*)w;      w += (size_t)n * 256 * 4;
    float* bufB = (float*)w;      w += (size_t)n * 256 * 4;
    float* dinv = (float*)w;      w += (size_t)n * 4;
    int* cnt = (int*)w;           w += (size_t)n * 4;
    int* row_start = (int*)w;     w += (size_t)n * 4;
    int* cursor = (int*)w;        w += (size_t)n * 4;
    int* csr_src = (int*)w;       w += (size_t)e * 4;
    int* counter = (int*)w;       w += 256;
    float* balance = (float*)w;   w += 480 * 4;
    short* w0h = (short*)w;       w += 256 * 256 * 2;
    short* w0l = (short*)w;       w += 256 * 256 * 2;
    short* w1h = (short*)w;       w += 256 * 256 * 2;
    short* w1l = (short*)w;       w += 256 * 256 * 2;
    short* w2h = (short*)w;       w += 128 * 256 * 2;
    short* w2l = (short*)w;       w += 128 * 256 * 2;
    short* ch  = (short*)w;       w += 128 * 256 * 2;
    short* cl  = (short*)w;       w += 128 * 256 * 2;

    short* xh = (short*)bufA;
    short* xl = xh + (size_t)n * 256;
    short* h1h = (short*)bufA;
    short* h1l = h1h + (size_t)n * 256;
    short* h2h = (short*)bufA;
    short* h2l = h2h + (size_t)n * 256;
    short* h3h = (short*)bufB;
    short* h3l = h3h + (size_t)n * 256;

    const int tb = 256;
    k_init<<<(n + tb - 1) / tb, tb, 0, stream>>>(cnt, cursor, counter, balance, n);
    k_count<<<(e + tb - 1) / tb, tb, 0, stream>>>(dst, cnt, e);
    k_allocdinv<<<(n + tb - 1) / tb, tb, 0, stream>>>(cnt, row_start, counter, dinv, n);
    k_fill<<<(e + tb - 1) / tb, tb, 0, stream>>>(src, dst, row_start, cursor, csr_src, e);

    k_splitWC<<<196608 / tb, tb, 0, stream>>>(W0, W1, W2, cent, w0h, w0l, w1h, w1l,
                                              w2h, w2l, ch, cl);
    k_splitA<<<(n * 32 + tb - 1) / tb, tb, 0, stream>>>(x, xh, xl, n * 32);

    dim3 g1((n + 127) / 128, 2);
    k_gemm_bf16s<<<g1, 256, 0, stream>>>(xh, xl, w0h, w0l, dinv, bufB, n, 256);
    k_agg4<true, 1><<<(n + 3) / 4, 256, 0, stream>>>(bufB, dinv, csr_src, row_start,
                                                     cnt, b0, nullptr, h1h, h1l, n);
    k_gemm_bf16s<<<g1, 256, 0, stream>>>(h1h, h1l, w1h, w1l, dinv, bufB, n, 256);
    k_agg4<true, 1><<<(n + 3) / 4, 256, 0, stream>>>(bufB, dinv, csr_src, row_start,
                                                     cnt, b1, nullptr, h2h, h2l, n);

    dim3 gq((n + 127) / 128, 4);
    k_quant7<<<gq, 256, 0, stream>>>(h2h, h2l, ch, cl, cent, h3h, h3l, balance, n);

    dim3 g3((n + 127) / 128, 1);
    k_gemm_bf16s<<<g3, 256, 0, stream>>>(h3h, h3l, w2h, w2l, dinv, bufA, n, 128);
    k_agg2<<<(n + 3) / 4, 256, 0, stream>>>(bufA, dinv, csr_src, row_start,
                                            cnt, b2, out, n);
    k_reg<<<1, 512, 0, stream>>>(balance, out + (size_t)n * 128, 1.0f / (float)n);
}